// Round 1
// baseline (60.271 us; speedup 1.0000x reference)
//
#include <hip/hip_runtime.h>

// WealthRNN: per-element nonlinear scan, S=1024 steps, B=16384 independent lanes.
// Memory-bound: 192 MiB single-pass -> ~30us floor at 6.3 TB/s.
// One thread per element; 256 blocks x 64 threads = 1 wave on each of 256 CUs.
// Depth-16 register prefetch pipeline (static indexing, stays in VGPRs).

#define S_LEN 1024
#define B_LEN 16384
#define PF 16

__device__ __forceinline__ float step_fn(float h, float x, float r,
                                         float win, float wh,
                                         float c1, float c2, float c3,
                                         float wf1, float wf2) {
    // h_adj = h*(1+r) / (1+h*r)
    float inv   = __builtin_amdgcn_rcpf(fmaf(h, r, 1.0f));
    float h_adj = fmaf(h, r, h) * inv;
    // ingate = x*w_in + w_h*h_adj - (pi_bar - b_h)
    float ingate = fmaf(wh, h_adj, fmaf(x, win, c1));
    float t  = fmaxf(ingate, 0.0f);
    // ingate2 = w_fc1*relu(ingate) + 2*b_h
    float g2 = fmaf(wf1, t, c2);
    float t2 = fmaxf(g2, 0.0f);
    // h_new = w_fc2*relu(ingate2) + pi_bar + b_h
    return fmaf(wf2, t2, c3);
}

__global__ __launch_bounds__(64) void wealth_rnn_kernel(
    const float* __restrict__ inputs,    // [S, B]
    const float* __restrict__ returns,   // [S-1, B]
    const float* __restrict__ target,    // [1]
    const float* __restrict__ w_in_p,    // [1]
    const float* __restrict__ w_h_p,     // [1]
    const float* __restrict__ b_h_p,     // [1]
    const float* __restrict__ w_fc1_p,   // [1]
    const float* __restrict__ w_fc2_p,   // [1]
    float* __restrict__ out)             // [S*B] output, then [B] hT
{
    const int b = blockIdx.x * 64 + threadIdx.x;

    const float pi_bar = target[0];
    const float win = w_in_p[0];
    const float wh  = w_h_p[0];
    const float bh  = b_h_p[0];
    const float wf1 = w_fc1_p[0];
    const float wf2 = w_fc2_p[0];
    const float c1 = bh - pi_bar;       // -(pi_bar - b_h)
    const float c2 = 2.0f * bh;
    const float c3 = pi_bar + bh;

    // step 0: h = inputs[0]
    float h = inputs[b];
    out[b] = h;

    // prologue: prefetch steps 1..PF
    float xb[PF], rb[PF];
#pragma unroll
    for (int d = 0; d < PF; ++d) {
        xb[d] = inputs[(1 + d) * B_LEN + b];
        rb[d] = returns[d * B_LEN + b];
    }

    int i = 1;
    // main pipelined loop: consume slot d (step i+d), prefetch step i+PF+d
    for (; i + 2 * PF <= S_LEN; i += PF) {
#pragma unroll
        for (int d = 0; d < PF; ++d) {
            const float x = xb[d];
            const float r = rb[d];
            xb[d] = inputs[(i + PF + d) * B_LEN + b];
            rb[d] = returns[(i + PF + d - 1) * B_LEN + b];
            h = step_fn(h, x, r, win, wh, c1, c2, c3, wf1, wf2);
            out[(i + d) * B_LEN + b] = h;
        }
    }

    // buffered tail: the PF steps already prefetched (i .. i+PF-1, all < S)
#pragma unroll
    for (int d = 0; d < PF; ++d) {
        h = step_fn(h, xb[d], rb[d], win, wh, c1, c2, c3, wf1, wf2);
        out[(i + d) * B_LEN + b] = h;
    }
    i += PF;

    // direct tail: remaining steps (wave-uniform guard)
#pragma unroll
    for (int d = 0; d < PF; ++d) {
        const int ii = i + d;
        if (ii < S_LEN) {
            const float x = inputs[ii * B_LEN + b];
            const float r = returns[(ii - 1) * B_LEN + b];
            h = step_fn(h, x, r, win, wh, c1, c2, c3, wf1, wf2);
            out[ii * B_LEN + b] = h;
        }
    }

    // hT
    out[S_LEN * B_LEN + b] = h;
}

extern "C" void kernel_launch(void* const* d_in, const int* in_sizes, int n_in,
                              void* d_out, int out_size, void* d_ws, size_t ws_size,
                              hipStream_t stream) {
    const float* inputs  = (const float*)d_in[0];
    const float* returns = (const float*)d_in[1];
    const float* target  = (const float*)d_in[2];
    const float* w_in    = (const float*)d_in[3];
    const float* w_h     = (const float*)d_in[4];
    const float* b_h     = (const float*)d_in[5];
    const float* w_fc1   = (const float*)d_in[6];
    const float* w_fc2   = (const float*)d_in[7];
    float* out = (float*)d_out;

    dim3 grid(B_LEN / 64);
    dim3 block(64);
    hipLaunchKernelGGL(wealth_rnn_kernel, grid, block, 0, stream,
                       inputs, returns, target, w_in, w_h, b_h, w_fc1, w_fc2, out);
}